// Round 1
// baseline (589.122 us; speedup 1.0000x reference)
//
#include <hip/hip_runtime.h>

// Problem constants (fixed by setup_inputs)
#define N_  2
#define C_  12
#define D_  8
#define HG  16
#define WG  16
#define H_  2048
#define W_  2048
#define HW_ (H_*W_)

// Prepass: transpose grid [N,C,D,Hg,Wg] -> T [N,D,Hg,Wg,C]
// so the 12 channels of one (z,y,x) cell are contiguous (48 B, 16B-aligned).
__global__ __launch_bounds__(256) void transpose_grid_k(const float* __restrict__ g,
                                                        float* __restrict__ T) {
    int i = blockIdx.x * 256 + threadIdx.x;
    if (i >= N_ * C_ * D_ * HG * WG) return;
    // input layout [n][c][z][y][x], x fastest
    int x = i & (WG - 1); int t = i >> 4;
    int y = t & (HG - 1); t >>= 4;
    int z = t & (D_ - 1); t >>= 3;
    int c = t % C_;
    int n = t / C_;
    T[(((n * D_ + z) * HG + y) * WG + x) * C_ + c] = g[i];
}

__global__ __launch_bounds__(256) void slice_k(const float* __restrict__ T,
                                               const float* __restrict__ guide,
                                               float* __restrict__ out) {
    int p = blockIdx.x * 256 + threadIdx.x;           // pixel id, [0, N*H*W)
    int n  = p >> 22;                                 // H*W = 2^22
    int hw = p & (HW_ - 1);
    int h  = hw >> 11;                                // W = 2^11
    int w  = hw & (W_ - 1);

    float g = guide[p];                               // guidemap [N,1,H,W] flat == p

    // Reference math, exact fp32 sequence:
    // coords[...,0] = hgm (from h) -> ix indexes Wg
    // coords[...,1] = wgm (from w) -> iy indexes Hg
    // coords[...,2] = guide        -> iz indexes D
    float xg = (float)h / (H_ - 1) * 2.0f - 1.0f;
    float yg = (float)w / (W_ - 1) * 2.0f - 1.0f;
    float zg = g;

    float ix = (xg + 1.0f) * 0.5f * (WG - 1);
    float iy = (yg + 1.0f) * 0.5f * (HG - 1);
    float iz = (zg + 1.0f) * 0.5f * (D_ - 1);

    float ix0f = floorf(ix), iy0f = floorf(iy), iz0f = floorf(iz);
    float fx = ix - ix0f, fy = iy - iy0f, fz = iz - iz0f;
    int ix0 = (int)ix0f, iy0 = (int)iy0f, iz0 = (int)iz0f;

    // per-axis weights folded with validity mask (zeros-padding semantics)
    float wx[2], wy[2], wz[2];
    int   xo[2], yo[2], zo[2];
    {
        int x0 = ix0, x1 = ix0 + 1;
        wx[0] = (1.0f - fx) * ((x0 >= 0 && x0 < WG) ? 1.0f : 0.0f);
        wx[1] = fx          * ((x1 >= 0 && x1 < WG) ? 1.0f : 0.0f);
        xo[0] = min(max(x0, 0), WG - 1) * C_;
        xo[1] = min(max(x1, 0), WG - 1) * C_;

        int y0 = iy0, y1 = iy0 + 1;
        wy[0] = (1.0f - fy) * ((y0 >= 0 && y0 < HG) ? 1.0f : 0.0f);
        wy[1] = fy          * ((y1 >= 0 && y1 < HG) ? 1.0f : 0.0f);
        yo[0] = min(max(y0, 0), HG - 1) * (WG * C_);
        yo[1] = min(max(y1, 0), HG - 1) * (WG * C_);

        int z0 = iz0, z1 = iz0 + 1;
        wz[0] = (1.0f - fz) * ((z0 >= 0 && z0 < D_) ? 1.0f : 0.0f);
        wz[1] = fz          * ((z1 >= 0 && z1 < D_) ? 1.0f : 0.0f);
        zo[0] = min(max(z0, 0), D_ - 1) * (HG * WG * C_);
        zo[1] = min(max(z1, 0), D_ - 1) * (HG * WG * C_);
    }

    const float* Tn = T + n * (D_ * HG * WG * C_);

    float4 a0 = {0.f, 0.f, 0.f, 0.f};
    float4 a1 = {0.f, 0.f, 0.f, 0.f};
    float4 a2 = {0.f, 0.f, 0.f, 0.f};

#pragma unroll
    for (int dz = 0; dz < 2; ++dz) {
#pragma unroll
        for (int dy = 0; dy < 2; ++dy) {
#pragma unroll
            for (int dx = 0; dx < 2; ++dx) {
                float wgt = wx[dx] * wy[dy] * wz[dz];
                const float* s = Tn + zo[dz] + yo[dy] + xo[dx];
                float4 s0 = *(const float4*)(s);
                float4 s1 = *(const float4*)(s + 4);
                float4 s2 = *(const float4*)(s + 8);
                a0.x = fmaf(wgt, s0.x, a0.x); a0.y = fmaf(wgt, s0.y, a0.y);
                a0.z = fmaf(wgt, s0.z, a0.z); a0.w = fmaf(wgt, s0.w, a0.w);
                a1.x = fmaf(wgt, s1.x, a1.x); a1.y = fmaf(wgt, s1.y, a1.y);
                a1.z = fmaf(wgt, s1.z, a1.z); a1.w = fmaf(wgt, s1.w, a1.w);
                a2.x = fmaf(wgt, s2.x, a2.x); a2.y = fmaf(wgt, s2.y, a2.y);
                a2.z = fmaf(wgt, s2.z, a2.z); a2.w = fmaf(wgt, s2.w, a2.w);
            }
        }
    }

    // out[n][c][h][w], one coalesced dword store per channel plane
    int ob = n * (C_ * HW_) + h * W_ + w;
    out[ob + 0  * HW_] = a0.x;
    out[ob + 1  * HW_] = a0.y;
    out[ob + 2  * HW_] = a0.z;
    out[ob + 3  * HW_] = a0.w;
    out[ob + 4  * HW_] = a1.x;
    out[ob + 5  * HW_] = a1.y;
    out[ob + 6  * HW_] = a1.z;
    out[ob + 7  * HW_] = a1.w;
    out[ob + 8  * HW_] = a2.x;
    out[ob + 9  * HW_] = a2.y;
    out[ob + 10 * HW_] = a2.z;
    out[ob + 11 * HW_] = a2.w;
}

extern "C" void kernel_launch(void* const* d_in, const int* in_sizes, int n_in,
                              void* d_out, int out_size, void* d_ws, size_t ws_size,
                              hipStream_t stream) {
    const float* grid  = (const float*)d_in[0];  // [2,12,8,16,16]
    const float* guide = (const float*)d_in[1];  // [2,1,2048,2048]
    float* out = (float*)d_out;                  // [2,12,2048,2048]
    float* T   = (float*)d_ws;                   // 49152 floats = 192 KiB scratch

    hipLaunchKernelGGL(transpose_grid_k, dim3(192), dim3(256), 0, stream, grid, T);
    hipLaunchKernelGGL(slice_k, dim3((N_ * HW_) / 256), dim3(256), 0, stream,
                       T, guide, out);
}

// Round 2
// 439.746 us; speedup vs baseline: 1.3397x; 1.3397x over previous
//
#include <hip/hip_runtime.h>

// Problem constants (fixed by setup_inputs)
#define N_  2
#define C_  12
#define D_  8
#define HG  16
#define WG  16
#define H_  2048
#define W_  2048
#define HW_ (H_*W_)

// Prepass: transpose grid [N,C,D,Hg,Wg] -> T [N,D,Hg,Wg,C]
// so the 12 channels of one (z,y,x) cell are contiguous (48 B, 16B-aligned).
__global__ __launch_bounds__(256) void transpose_grid_k(const float* __restrict__ g,
                                                        float* __restrict__ T) {
    int i = blockIdx.x * 256 + threadIdx.x;
    if (i >= N_ * C_ * D_ * HG * WG) return;
    int x = i & (WG - 1); int t = i >> 4;
    int y = t & (HG - 1); t >>= 4;
    int z = t & (D_ - 1); t >>= 3;
    int c = t % C_;
    int n = t / C_;
    T[(((n * D_ + z) * HG + y) * WG + x) * C_ + c] = g[i];
}

// One block = 1024 pixels of one image row (h uniform within block).
// x-interpolation folded into LDS staging: Lg[z][y][c], 1536 floats.
// Each thread: 4 pixels at stride 256 -> per-q stores are wave-contiguous.
__global__ __launch_bounds__(256) void slice_k(const float* __restrict__ T,
                                               const float* __restrict__ guide,
                                               float* __restrict__ out) {
    __shared__ float Lg[D_ * HG * C_];   // 6 KiB

    const int tid   = threadIdx.x;
    const int b     = blockIdx.x;
    const int wseg  = b & 1;             // which half of the row
    const int rowid = b >> 1;
    const int h     = rowid & (H_ - 1);
    const int n     = rowid >> 11;

    // ---- x interpolation factors (uniform across block) ----
    float xg   = (float)h / (H_ - 1) * 2.0f - 1.0f;
    float ixf  = (xg + 1.0f) * 0.5f * (WG - 1);
    float ix0f = floorf(ixf);
    float fx   = ixf - ix0f;
    int   x0   = (int)ix0f;
    int   x1   = x0 + 1;
    float wx0  = (1.0f - fx) * ((x0 >= 0 && x0 < WG) ? 1.0f : 0.0f);
    float wx1  = fx          * ((x1 >= 0 && x1 < WG) ? 1.0f : 0.0f);
    x0 = min(max(x0, 0), WG - 1);
    x1 = min(max(x1, 0), WG - 1);

    // ---- stage x-interpolated grid into LDS ----
    const float* Tn = T + n * (D_ * HG * WG * C_);
    for (int i = tid; i < D_ * HG * C_; i += 256) {
        int c  = i % C_;
        int zy = i / C_;                              // z*16 + y
        const float* s = Tn + zy * (WG * C_) + c;
        Lg[i] = wx0 * s[x0 * C_] + wx1 * s[x1 * C_];
    }
    __syncthreads();

    const int w0     = wseg * 1024;
    const int p_base = n * HW_ + h * W_ + w0 + tid;   // guide index, q=0
    const int o_base = n * (C_ * HW_) + h * W_ + w0 + tid;

#pragma unroll
    for (int q = 0; q < 4; ++q) {
        const int w = w0 + q * 256 + tid;
        const float gq = __builtin_nontemporal_load(guide + p_base + q * 256);

        // y interpolation
        float yg   = (float)w / (W_ - 1) * 2.0f - 1.0f;
        float iyf  = (yg + 1.0f) * 0.5f * (HG - 1);
        float iy0f = floorf(iyf);
        float fy   = iyf - iy0f;
        int   y0   = (int)iy0f, y1 = y0 + 1;
        float wy0  = (1.0f - fy) * ((y0 >= 0 && y0 < HG) ? 1.0f : 0.0f);
        float wy1  = fy          * ((y1 >= 0 && y1 < HG) ? 1.0f : 0.0f);
        y0 = min(max(y0, 0), HG - 1);
        y1 = min(max(y1, 0), HG - 1);

        // z interpolation (from guide)
        float izf  = (gq + 1.0f) * 0.5f * (D_ - 1);
        float iz0f = floorf(izf);
        float fz   = izf - iz0f;
        int   z0   = (int)iz0f, z1 = z0 + 1;
        float wz0  = (1.0f - fz) * ((z0 >= 0 && z0 < D_) ? 1.0f : 0.0f);
        float wz1  = fz          * ((z1 >= 0 && z1 < D_) ? 1.0f : 0.0f);
        z0 = min(max(z0, 0), D_ - 1);
        z1 = min(max(z1, 0), D_ - 1);

        const int o00 = (z0 * HG + y0) * C_;
        const int o01 = (z0 * HG + y1) * C_;
        const int o10 = (z1 * HG + y0) * C_;
        const int o11 = (z1 * HG + y1) * C_;
        const float w00 = wz0 * wy0, w01 = wz0 * wy1;
        const float w10 = wz1 * wy0, w11 = wz1 * wy1;

        const int ob = o_base + q * 256;
#pragma unroll
        for (int j = 0; j < 3; ++j) {
            float4 c00 = *(const float4*)(Lg + o00 + j * 4);
            float4 c01 = *(const float4*)(Lg + o01 + j * 4);
            float4 c10 = *(const float4*)(Lg + o10 + j * 4);
            float4 c11 = *(const float4*)(Lg + o11 + j * 4);
            float v0 = fmaf(w00, c00.x, fmaf(w01, c01.x, fmaf(w10, c10.x, w11 * c11.x)));
            float v1 = fmaf(w00, c00.y, fmaf(w01, c01.y, fmaf(w10, c10.y, w11 * c11.y)));
            float v2 = fmaf(w00, c00.z, fmaf(w01, c01.z, fmaf(w10, c10.z, w11 * c11.z)));
            float v3 = fmaf(w00, c00.w, fmaf(w01, c01.w, fmaf(w10, c10.w, w11 * c11.w)));
            __builtin_nontemporal_store(v0, out + ob + (j * 4 + 0) * HW_);
            __builtin_nontemporal_store(v1, out + ob + (j * 4 + 1) * HW_);
            __builtin_nontemporal_store(v2, out + ob + (j * 4 + 2) * HW_);
            __builtin_nontemporal_store(v3, out + ob + (j * 4 + 3) * HW_);
        }
    }
}

extern "C" void kernel_launch(void* const* d_in, const int* in_sizes, int n_in,
                              void* d_out, int out_size, void* d_ws, size_t ws_size,
                              hipStream_t stream) {
    const float* grid  = (const float*)d_in[0];  // [2,12,8,16,16]
    const float* guide = (const float*)d_in[1];  // [2,1,2048,2048]
    float* out = (float*)d_out;                  // [2,12,2048,2048]
    float* T   = (float*)d_ws;                   // 49152 floats = 192 KiB scratch

    hipLaunchKernelGGL(transpose_grid_k, dim3(192), dim3(256), 0, stream, grid, T);
    // blocks: 2 per row (1024 px each) x N*H rows
    hipLaunchKernelGGL(slice_k, dim3(N_ * H_ * 2), dim3(256), 0, stream,
                       T, guide, out);
}